// Round 3
// baseline (1506.903 us; speedup 1.0000x reference)
//
#include <hip/hip_runtime.h>
#include <math.h>

#define NS   512   // states
#define NO   1024  // observations
#define NB   64    // batch
#define TMAX 512

#define QREG 45    // uint4 chunks (8 fp16 k-values each) held in VGPRs: k 0..359
#define QLDS 19    // uint4 chunks held in LDS: k 360..511

typedef _Float16 h2v __attribute__((ext_vector_type(2)));

__device__ inline float wave_red_sum(float x) {
#pragma unroll
  for (int o = 32; o; o >>= 1) x += __shfl_xor(x, o, 64);
  return x;
}
__device__ inline float wave_red_max(float x) {
#pragma unroll
  for (int o = 32; o; o >>= 1) x = fmaxf(x, __shfl_xor(x, o, 64));
  return x;
}

__device__ inline float dot2u(unsigned int a, unsigned int b, float c) {
#if __has_builtin(__builtin_amdgcn_fdot2)
  return __builtin_amdgcn_fdot2(__builtin_bit_cast(h2v, a),
                                __builtin_bit_cast(h2v, b), c, false);
#else
  h2v av = __builtin_bit_cast(h2v, a), bv = __builtin_bit_cast(h2v, b);
  return c + (float)av.x * (float)bv.x + (float)av.y * (float)bv.y;
#endif
}

// P1: pi softmax -> pi_sm[512]
__global__ void k_pi(const float* __restrict__ pi, float* __restrict__ pi_sm) {
  __shared__ float red[8];
  int tid = threadIdx.x;
  float v = pi[tid];
  float m = wave_red_max(v);
  if ((tid & 63) == 0) red[tid >> 6] = m;
  __syncthreads();
  m = fmaxf(fmaxf(fmaxf(red[0], red[1]), fmaxf(red[2], red[3])),
            fmaxf(fmaxf(red[4], red[5]), fmaxf(red[6], red[7])));
  float e = __expf(v - m);
  float s = wave_red_sum(e);
  __syncthreads();
  if ((tid & 63) == 0) red[tid >> 6] = s;
  __syncthreads();
  s = red[0] + red[1] + red[2] + red[3] + red[4] + red[5] + red[6] + red[7];
  pi_sm[tid] = e / s;
}

// P2: column logsumexp of A (axis 0). One block (256 thr) per column. grid 512.
__global__ void k_colLse(const float* __restrict__ A, float* __restrict__ lseA) {
  __shared__ float redm[4];
  __shared__ float reds[4];
  int k = blockIdx.x, tid = threadIdx.x;
  float a0 = A[tid * NS + k], a1 = A[(tid + 256) * NS + k];
  float m = wave_red_max(fmaxf(a0, a1));
  if ((tid & 63) == 0) redm[tid >> 6] = m;
  __syncthreads();
  m = fmaxf(fmaxf(redm[0], redm[1]), fmaxf(redm[2], redm[3]));
  float s = __expf(a0 - m) + __expf(a1 - m);
  s = wave_red_sum(s);
  if ((tid & 63) == 0) reds[tid >> 6] = s;
  __syncthreads();
  s = reds[0] + reds[1] + reds[2] + reds[3];
  if (tid == 0) lseA[k] = m + __logf(s);
}

// P3: row logsumexp of E (axis 1). One block per row. grid 512 x 256.
__global__ void k_rowLseE(const float* __restrict__ E, float* __restrict__ lseE) {
  __shared__ float red[4];
  int i = blockIdx.x, tid = threadIdx.x;
  const float* row = E + i * NO;
  float a0 = row[tid], a1 = row[tid + 256], a2 = row[tid + 512], a3 = row[tid + 768];
  float m = fmaxf(fmaxf(a0, a1), fmaxf(a2, a3));
  m = wave_red_max(m);
  if ((tid & 63) == 0) red[tid >> 6] = m;
  __syncthreads();
  m = fmaxf(fmaxf(red[0], red[1]), fmaxf(red[2], red[3]));
  float s = __expf(a0 - m) + __expf(a1 - m) + __expf(a2 - m) + __expf(a3 - m);
  s = wave_red_sum(s);
  __syncthreads();
  if ((tid & 63) == 0) red[tid >> 6] = s;
  __syncthreads();
  s = red[0] + red[1] + red[2] + red[3];
  if (tid == 0) lseE[i] = m + __logf(s);
}

// P4: pack A_exp = exp(A - lseA[col]) fp16, chunk-major (see prev rounds).
__global__ void k_pack(const float* __restrict__ A, const float* __restrict__ lseA,
                       unsigned int* __restrict__ W) {
  int u = blockIdx.x * 512 + threadIdx.x;   // [0, 64*512*4)
  int q = u >> 11;
  int r = u & 2047;
  int i = r >> 2;
  int h = r & 3;
  int k0 = q * 8 + h * 2;
  float e0 = __expf(A[i * NS + k0]     - lseA[k0]);
  float e1 = __expf(A[i * NS + k0 + 1] - lseA[k0 + 1]);
  h2v p;
  p.x = (_Float16)e0;
  p.y = (_Float16)e1;
  W[u] = __builtin_bit_cast(unsigned int, p);
}

// Main forward: one block per batch, thread tid = output state i.
// A row i: 360 k-values pinned in VGPRs (per-component asm keep-alive blocks
// the compiler's load-sinking that was re-streaming A from L2 every step)
// + 152 in LDS.
//
// Deferred pow2 rescale, ONE barrier/step:
//   u_t = raw_t * 2^gexp_t,  raw_t = (A u_{t-1}) o em_t
//   sigma_t = sum(raw_t) reduced at step t, CONSUMED pre-dot at step t+1
//   log2 s_t = log2 sigma_t - log2 d_{t-1}  (telescopes exactly; gexp is an
//   exact power of two so no rounding enters the bookkeeping)
__global__ __launch_bounds__(512)
__attribute__((amdgpu_waves_per_eu(2, 2)))
void k_fwd(
    const float* __restrict__ E, const int* __restrict__ x,
    const int* __restrict__ Tlen, const float* __restrict__ pi_sm,
    const float* __restrict__ lseE, const uint4* __restrict__ Aall,
    float* __restrict__ out) {
  __shared__ uint4 Alds[QLDS * 512];            // 155648 B
  __shared__ uint4 vbuf[2][NS / 8];             // 2 KB ping-pong (fp16 u)
  __shared__ int xrow[TMAX];                    // 2 KB
  __shared__ __align__(16) float red[2][8];     // ping-pong partials
  int b = blockIdx.x, tid = threadIdx.x;

  // Load this row's A into registers (coalesced uint4) and LDS.
  uint4 areg[QREG];
#pragma unroll
  for (int q = 0; q < QREG; q++) areg[q] = Aall[q * 512 + tid];
#pragma unroll
  for (int q = 0; q < QREG; q++) {
    // pin each 32-bit component in a VGPR (128-bit tied operands are illegal)
    asm volatile("" : "+v"(areg[q].x), "+v"(areg[q].y),
                      "+v"(areg[q].z), "+v"(areg[q].w));
  }
#pragma unroll
  for (int q = 0; q < QLDS; q++) Alds[q * 512 + tid] = Aall[(QREG + q) * 512 + tid];

  for (int t = tid; t < TMAX; t += 512) xrow[t] = x[b * TMAX + t];

  float pi_i  = pi_sm[tid];
  float lse_i = lseE[tid];
  const float* Erow = E + tid * NO;
  int Tb = Tlen[b];
  float c = 0.f;        // log2-domain accumulator
  float Dlog = 0.f;     // log2 d_{t-1}
  int gexp_prev = 19;
  int cur = 0;
  __syncthreads();

  for (int t = 0; t < Tb; t++) {
    int nxt = cur ^ 1;
    float epre = Erow[xrow[t]];     // issued early; latency hides under dot
    int gexpw;
    if (t == 0) {
      gexpw = 19;
    } else {
      // consume previous step's sum (written to red[cur] before the barrier)
      const float4* rp = (const float4*)red[cur];
      float4 ra = rp[0], rb = rp[1];
      float sp = ((ra.x + ra.y) + (ra.z + ra.w)) + ((rb.x + rb.y) + (rb.z + rb.w));
      float ls = __log2f(sp);
      int e = ((__builtin_bit_cast(int, sp) >> 23) & 0xff) - 126;  // sp = m*2^e, m in [0.5,1)
      c += ls - Dlog;                 // += log2 s_{t-1}
      Dlog = (float)gexp_prev + ls;   // log2 d_{t-1}
      gexpw = 19 - gexp_prev - e;
    }
    float acc;
    if (t == 0) {
      acc = pi_i;
    } else {
      float a0 = 0.f, a1 = 0.f, a2 = 0.f, a3 = 0.f;
      const uint4* vp = vbuf[cur];
#pragma unroll
      for (int q = 0; q < QREG; q++) {
        uint4 vv = vp[q];                      // wave-uniform broadcast
        a0 = dot2u(areg[q].x, vv.x, a0);
        a1 = dot2u(areg[q].y, vv.y, a1);
        a2 = dot2u(areg[q].z, vv.z, a2);
        a3 = dot2u(areg[q].w, vv.w, a3);
      }
#pragma unroll
      for (int q = 0; q < QLDS; q++) {
        uint4 av = Alds[q * 512 + tid];        // private, conflict-free
        uint4 vv = vp[QREG + q];
        a0 = dot2u(av.x, vv.x, a0);
        a1 = dot2u(av.y, vv.y, a1);
        a2 = dot2u(av.z, vv.z, a2);
        a3 = dot2u(av.w, vv.w, a3);
      }
      acc = (a0 + a1) + (a2 + a3);
    }
    float em = __expf(epre - lse_i);
    float raw = acc * em;
    // write scaled u (exact pow2 scale); avg component ~1 -> fp16 sweet spot
    ((_Float16*)vbuf[nxt])[tid] = (_Float16)ldexpf(raw, gexpw);
    // reduce raw for next step's sigma
    float s = wave_red_sum(raw);
    if ((tid & 63) == 0) red[nxt][tid >> 6] = s;
    gexp_prev = gexpw;
    cur = nxt;
    __syncthreads();
  }
  // final: consume last step's sum
  {
    const float4* rp = (const float4*)red[cur];
    float4 ra = rp[0], rb = rp[1];
    float sp = ((ra.x + ra.y) + (ra.z + ra.w)) + ((rb.x + rb.y) + (rb.z + rb.w));
    c += __log2f(sp) - Dlog;
  }
  if (tid == 0) out[b] = c * 0.69314718055994530942f;
}

extern "C" void kernel_launch(void* const* d_in, const int* in_sizes, int n_in,
                              void* d_out, int out_size, void* d_ws, size_t ws_size,
                              hipStream_t stream) {
  const float* pi = (const float*)d_in[0];
  const float* A  = (const float*)d_in[1];
  const float* E  = (const float*)d_in[2];
  const int*   x  = (const int*)d_in[3];
  const int*   T  = (const int*)d_in[4];
  float* out = (float*)d_out;

  char* ws = (char*)d_ws;
  float*        pi_sm = (float*)(ws + 0);
  float*        lseA  = (float*)(ws + 2048);
  float*        lseE  = (float*)(ws + 4096);
  unsigned int* Apk   = (unsigned int*)(ws + 6144);  // 512*512 fp16 = 512 KB

  hipLaunchKernelGGL(k_pi,      dim3(1),   dim3(512), 0, stream, pi, pi_sm);
  hipLaunchKernelGGL(k_colLse,  dim3(512), dim3(256), 0, stream, A, lseA);
  hipLaunchKernelGGL(k_rowLseE, dim3(512), dim3(256), 0, stream, E, lseE);
  hipLaunchKernelGGL(k_pack,    dim3(256), dim3(512), 0, stream, A, lseA, Apk);
  hipLaunchKernelGGL(k_fwd,     dim3(64),  dim3(512), 0, stream,
                     E, x, T, pi_sm, lseE, (const uint4*)Apk, out);
}

// Round 4
// 1255.271 us; speedup vs baseline: 1.2005x; 1.2005x over previous
//
#include <hip/hip_runtime.h>
#include <math.h>

#define NS   512   // states
#define NO   1024  // observations
#define NB   64    // batch
#define TMAX 512

// Per-thread A: 32 fp16-pairs (64 k-values). 24 pairs in VGPRs, 8 in LDS.
#define QPR 24
#define QLD 8

typedef _Float16 h2v __attribute__((ext_vector_type(2)));

__device__ inline float wave_red_sum(float x) {
#pragma unroll
  for (int o = 32; o; o >>= 1) x += __shfl_xor(x, o, 64);
  return x;
}
__device__ inline float wave_red_max(float x) {
#pragma unroll
  for (int o = 32; o; o >>= 1) x = fmaxf(x, __shfl_xor(x, o, 64));
  return x;
}

__device__ inline float dot2u(unsigned int a, unsigned int b, float c) {
#if __has_builtin(__builtin_amdgcn_fdot2)
  return __builtin_amdgcn_fdot2(__builtin_bit_cast(h2v, a),
                                __builtin_bit_cast(h2v, b), c, false);
#else
  h2v av = __builtin_bit_cast(h2v, a), bv = __builtin_bit_cast(h2v, b);
  return c + (float)av.x * (float)bv.x + (float)av.y * (float)bv.y;
#endif
}

// P1: pi softmax -> pi_sm[512]
__global__ void k_pi(const float* __restrict__ pi, float* __restrict__ pi_sm) {
  __shared__ float red[8];
  int tid = threadIdx.x;
  float v = pi[tid];
  float m = wave_red_max(v);
  if ((tid & 63) == 0) red[tid >> 6] = m;
  __syncthreads();
  m = fmaxf(fmaxf(fmaxf(red[0], red[1]), fmaxf(red[2], red[3])),
            fmaxf(fmaxf(red[4], red[5]), fmaxf(red[6], red[7])));
  float e = __expf(v - m);
  float s = wave_red_sum(e);
  __syncthreads();
  if ((tid & 63) == 0) red[tid >> 6] = s;
  __syncthreads();
  s = red[0] + red[1] + red[2] + red[3] + red[4] + red[5] + red[6] + red[7];
  pi_sm[tid] = e / s;
}

// P2: column logsumexp of A (axis 0). One block (256 thr) per column. grid 512.
__global__ void k_colLse(const float* __restrict__ A, float* __restrict__ lseA) {
  __shared__ float redm[4];
  __shared__ float reds[4];
  int k = blockIdx.x, tid = threadIdx.x;
  float a0 = A[tid * NS + k], a1 = A[(tid + 256) * NS + k];
  float m = wave_red_max(fmaxf(a0, a1));
  if ((tid & 63) == 0) redm[tid >> 6] = m;
  __syncthreads();
  m = fmaxf(fmaxf(redm[0], redm[1]), fmaxf(redm[2], redm[3]));
  float s = __expf(a0 - m) + __expf(a1 - m);
  s = wave_red_sum(s);
  if ((tid & 63) == 0) reds[tid >> 6] = s;
  __syncthreads();
  s = reds[0] + reds[1] + reds[2] + reds[3];
  if (tid == 0) lseA[k] = m + __logf(s);
}

// P3: row logsumexp of E (axis 1). One block per row. grid 512 x 256.
__global__ void k_rowLseE(const float* __restrict__ E, float* __restrict__ lseE) {
  __shared__ float red[4];
  int i = blockIdx.x, tid = threadIdx.x;
  const float* row = E + i * NO;
  float a0 = row[tid], a1 = row[tid + 256], a2 = row[tid + 512], a3 = row[tid + 768];
  float m = fmaxf(fmaxf(a0, a1), fmaxf(a2, a3));
  m = wave_red_max(m);
  if ((tid & 63) == 0) red[tid >> 6] = m;
  __syncthreads();
  m = fmaxf(fmaxf(red[0], red[1]), fmaxf(red[2], red[3]));
  float s = __expf(a0 - m) + __expf(a1 - m) + __expf(a2 - m) + __expf(a3 - m);
  s = wave_red_sum(s);
  __syncthreads();
  if ((tid & 63) == 0) red[tid >> 6] = s;
  __syncthreads();
  s = red[0] + red[1] + red[2] + red[3];
  if (tid == 0) lseE[i] = m + __logf(s);
}

// P4: pack A_exp = exp(A - lseA[col]) fp16 for the k-split layout.
// Thread t of k_fwd: wave w=t>>6, lane l=t&63, kk=w&7, rr=w>>3.
// Chunk (m,t) = uint4 { rows 256rr+64r+l (r=0..3) x cols (64kk+2m, 64kk+2m+1) }.
// Word index u = (m*1024 + t)*4 + r. grid 256 x 512.
__global__ void k_pack2(const float* __restrict__ A, const float* __restrict__ lseA,
                        unsigned int* __restrict__ W) {
  int u = blockIdx.x * 512 + threadIdx.x;   // [0, 131072)
  int r = u & 3;
  int mt = u >> 2;
  int t = mt & 1023;
  int m = mt >> 10;
  int w = t >> 6, l = t & 63;
  int kk = w & 7, rr = w >> 3;
  int i = 256 * rr + 64 * r + l;
  int k0 = 64 * kk + 2 * m;
  float e0 = __expf(A[i * NS + k0]     - lseA[k0]);
  float e1 = __expf(A[i * NS + k0 + 1] - lseA[k0 + 1]);
  h2v p;
  p.x = (_Float16)e0;
  p.y = (_Float16)e1;
  W[u] = __builtin_bit_cast(unsigned int, p);
}

// Main forward: one block (1024 thr, 16 waves) per batch.
// Wave w = (kk = w&7, rr = w>>3): k-slice [64kk, 64kk+64), rows [256rr, 256rr+256).
// Lane l handles rows {256rr + 64r + l, r=0..3}. A fully on-CU:
// 24 pairs/thread in VGPRs (96 regs, ~124 total < 128 hard cap at 16 waves)
// + 8 pairs/thread in LDS (128 KB). v broadcast by v_readlane from wave-local
// regs (loaded with ONE ds_read_b32/wave/step) - removes the uniform-b128
// LDS storm that bounded the 512-thread design.
// Deferred pow2 rescale (validated r3): u_t = raw_t*2^g, sigma reduced at t,
// consumed pre-dot at t+1; bookkeeping telescopes exactly.
__global__ __launch_bounds__(1024) void k_fwd(
    const float* __restrict__ E, const int* __restrict__ x,
    const int* __restrict__ Tlen, const float* __restrict__ pi_sm,
    const float* __restrict__ lseE, const uint4* __restrict__ Aall,
    float* __restrict__ out) {
  __shared__ uint4 Alds[QLD * 1024];            // 131072 B
  __shared__ float Pf[8 * 512];                 // 16 KB partials P[kk][i]
  __shared__ unsigned int ubuf[2][256];         // 2 KB ping-pong packed u pairs
  __shared__ int xrow[TMAX];                    // 2 KB
  __shared__ __align__(16) float red[2][8];     // ping-pong sigma partials
  int b = blockIdx.x, tid = threadIdx.x;
  int w = tid >> 6, l = tid & 63;
  int kk = w & 7, rr = w >> 3;
  bool owner = (w < 8);                         // threads 0..511 own output i=tid

  // Prologue: load A chunks (coalesced uint4) into regs and LDS.
  uint4 areg[QPR];
#pragma unroll
  for (int m = 0; m < QPR; m++) areg[m] = Aall[m * 1024 + tid];
#pragma unroll
  for (int m = 0; m < QLD; m++) Alds[m * 1024 + tid] = Aall[(QPR + m) * 1024 + tid];

  for (int j = tid; j < TMAX; j += 1024) xrow[j] = x[b * TMAX + j];

  float pi_i = 0.f, lse_i = 0.f;
  const float* Erow = E;
  if (owner) {
    pi_i  = pi_sm[tid];
    lse_i = lseE[tid];
    Erow  = E + tid * NO;
  }
  int Tb = Tlen[b];
  float c = 0.f;        // log2-domain accumulator
  float Dlog = 0.f;     // log2 d_{t-1}
  int gexp_prev = 19;
  int cur = 0;
  __syncthreads();

  for (int t = 0; t < Tb; t++) {
    float epre = owner ? Erow[xrow[t]] : 0.f;   // gather early, hides under dot
    int gexpw = 19;
    if (t) {
      if (owner) {
        // consume previous step's sigma (deferred; latency hidden by dot)
        const float4* rp = (const float4*)red[cur];
        float4 ra = rp[0], rb = rp[1];
        float sp = ((ra.x + ra.y) + (ra.z + ra.w)) + ((rb.x + rb.y) + (rb.z + rb.w));
        float ls = __log2f(sp);
        int e = ((__builtin_bit_cast(int, sp) >> 23) & 0xff) - 126;
        c += ls - Dlog;
        Dlog = (float)gexp_prev + ls;
        gexpw = 19 - gexp_prev - e;
      }
      // wave-local u pairs: lane m holds pair 32*kk+m (lanes 32..63 duplicate)
      unsigned int upair = ubuf[cur][kk * 32 + (l & 31)];
      int up = (int)upair;
      float a0 = 0.f, a1 = 0.f, a2 = 0.f, a3 = 0.f;
#pragma unroll
      for (int m = 0; m < QPR; m++) {
        unsigned int s = (unsigned int)__builtin_amdgcn_readlane(up, m);
        a0 = dot2u(areg[m].x, s, a0);
        a1 = dot2u(areg[m].y, s, a1);
        a2 = dot2u(areg[m].z, s, a2);
        a3 = dot2u(areg[m].w, s, a3);
      }
#pragma unroll
      for (int m = 0; m < QLD; m++) {
        uint4 av = Alds[m * 1024 + tid];
        unsigned int s = (unsigned int)__builtin_amdgcn_readlane(up, QPR + m);
        a0 = dot2u(av.x, s, a0);
        a1 = dot2u(av.y, s, a1);
        a2 = dot2u(av.z, s, a2);
        a3 = dot2u(av.w, s, a3);
      }
      // partials: P[kk][256rr + 64r + l]  (conflict-free: lanes consecutive)
      int pbase = kk * 512 + 256 * rr + l;
      Pf[pbase]       = a0;
      Pf[pbase + 64]  = a1;
      Pf[pbase + 128] = a2;
      Pf[pbase + 192] = a3;
    }
    __syncthreads();   // bar1: partials visible
    if (owner) {
      float em = __expf(epre - lse_i);
      float raw;
      if (t) {
        float s0 = Pf[tid]          + Pf[512 + tid];
        float s1 = Pf[1024 + tid]   + Pf[1536 + tid];
        float s2 = Pf[2048 + tid]   + Pf[2560 + tid];
        float s3 = Pf[3072 + tid]   + Pf[3584 + tid];
        raw = ((s0 + s1) + (s2 + s3)) * em;
      } else {
        raw = pi_i * em;
      }
      // sigma for next step (deferred consumption)
      float s = wave_red_sum(raw);
      if (l == 0) red[cur ^ 1][kk] = s;
      // write scaled u (exact pow2): pack fp16 pairs, even lanes store
      float us = ldexpf(raw, gexpw);
      unsigned short h = __builtin_bit_cast(unsigned short, (_Float16)us);
      int oth = __shfl_xor((int)h, 1, 64);
      if (!(l & 1)) ubuf[cur ^ 1][tid >> 1] = (unsigned int)h | ((unsigned int)oth << 16);
      gexp_prev = gexpw;
    }
    __syncthreads();   // bar2: u + sigma visible for next step
    cur ^= 1;
  }
  // epilogue: consume last step's sigma
  if (tid == 0) {
    const float4* rp = (const float4*)red[cur];
    float4 ra = rp[0], rb = rp[1];
    float sp = ((ra.x + ra.y) + (ra.z + ra.w)) + ((rb.x + rb.y) + (rb.z + rb.w));
    c += __log2f(sp) - Dlog;
    out[b] = c * 0.69314718055994530942f;
  }
}

extern "C" void kernel_launch(void* const* d_in, const int* in_sizes, int n_in,
                              void* d_out, int out_size, void* d_ws, size_t ws_size,
                              hipStream_t stream) {
  const float* pi = (const float*)d_in[0];
  const float* A  = (const float*)d_in[1];
  const float* E  = (const float*)d_in[2];
  const int*   x  = (const int*)d_in[3];
  const int*   T  = (const int*)d_in[4];
  float* out = (float*)d_out;

  char* ws = (char*)d_ws;
  float*        pi_sm = (float*)(ws + 0);
  float*        lseA  = (float*)(ws + 2048);
  float*        lseE  = (float*)(ws + 4096);
  unsigned int* Apk   = (unsigned int*)(ws + 6144);  // 512*512 fp16 = 512 KB

  hipLaunchKernelGGL(k_pi,      dim3(1),   dim3(512),  0, stream, pi, pi_sm);
  hipLaunchKernelGGL(k_colLse,  dim3(512), dim3(256),  0, stream, A, lseA);
  hipLaunchKernelGGL(k_rowLseE, dim3(512), dim3(256),  0, stream, E, lseE);
  hipLaunchKernelGGL(k_pack2,   dim3(256), dim3(512),  0, stream, A, lseA, Apk);
  hipLaunchKernelGGL(k_fwd,     dim3(64),  dim3(1024), 0, stream,
                     E, x, T, pi_sm, lseE, (const uint4*)Apk, out);
}